// Round 16
// baseline (548.781 us; speedup 1.0000x reference)
//
#include <hip/hip_runtime.h>

#define BATCH 16
#define TILE 2048
#define BKT 512          // nodes per bucket (power of two)
#define BKT_SHIFT 9
#define NCHUNK 256       // blocks for bhist/binscatter (bscan loops NCHUNK per column)

// native clang ext-vectors for __builtin_nontemporal_* (HIP_vector_type is rejected)
typedef int   i4 __attribute__((ext_vector_type(4)));
typedef float f4 __attribute__((ext_vector_type(4)));

__device__ __forceinline__ float fast_tanh(float v) {
    float a = fabsf(v);
    float e = __expf(2.0f * a);
    float t = 1.0f - 2.0f / (e + 1.0f);
    return copysignf(t, v);
}

__device__ __forceinline__ float blend(float lin, float alpha) {
    return lin + alpha * (fast_tanh(lin) - lin);
}

// xT[n*B+b] = x[b*N+n]
__global__ __launch_bounds__(256) void k_transpose(const float* __restrict__ x,
                                                   float* __restrict__ xT, int N) {
    int n = blockIdx.x * blockDim.x + threadIdx.x;
    if (n >= N) return;
    float v[BATCH];
#pragma unroll
    for (int b = 0; b < BATCH; ++b) v[b] = x[(size_t)b * N + n];
    float4* dst = (float4*)(xT + (size_t)n * BATCH);
#pragma unroll
    for (int i = 0; i < BATCH / 4; ++i)
        dst[i] = make_float4(v[4 * i], v[4 * i + 1], v[4 * i + 2], v[4 * i + 3]);
}

// per-block bucket histogram (LDS counters), written to blkcnt[block][NB]
__global__ __launch_bounds__(256) void k_bhist(const int* __restrict__ dst,
                                               int* __restrict__ blkcnt,
                                               int E, int CHUNK, int NB) {
    extern __shared__ unsigned bc[];  // NB u32
    for (int i = threadIdx.x; i < NB; i += 256) bc[i] = 0u;
    __syncthreads();
    int beg = blockIdx.x * CHUNK, end = min(E, beg + CHUNK);
    for (int base = beg + (int)threadIdx.x * 4; base < end; base += 256 * 4) {
        if (base + 3 < end) {
            i4 d = __builtin_nontemporal_load((const i4*)(dst + base));
            atomicAdd(&bc[(unsigned)d.x >> BKT_SHIFT], 1u);
            atomicAdd(&bc[(unsigned)d.y >> BKT_SHIFT], 1u);
            atomicAdd(&bc[(unsigned)d.z >> BKT_SHIFT], 1u);
            atomicAdd(&bc[(unsigned)d.w >> BKT_SHIFT], 1u);
        } else {
            for (int e = base; e < end; ++e) atomicAdd(&bc[(unsigned)dst[e] >> BKT_SHIFT], 1u);
        }
    }
    __syncthreads();
    int* bo = blkcnt + (size_t)blockIdx.x * NB;
    for (int i = threadIdx.x; i < NB; i += 256) bo[i] = (int)bc[i];
}

// single block: column-scan blkcnt (exclusive, in place) + bucket bases. NB <= 256.
__global__ __launch_bounds__(256) void k_bscan(int* __restrict__ blkcnt,
                                               int* __restrict__ bucketBase,
                                               int NB, int nchunk, int E) {
    int t = threadIdx.x;
    int run = 0;
    if (t < NB) {
        for (int blk = 0; blk < nchunk; ++blk) {
            size_t i = (size_t)blk * NB + t;
            int c = blkcnt[i];
            blkcnt[i] = run;
            run += c;
        }
    }
    __shared__ int sh[256];
    int tot = run;
    sh[t] = tot;
    __syncthreads();
    for (int off = 1; off < 256; off <<= 1) {
        int add = (t >= off) ? sh[t - off] : 0;
        __syncthreads();
        sh[t] += add;
        __syncthreads();
    }
    if (t < NB) bucketBase[t] = sh[t] - tot;  // exclusive
    if (t == 0) bucketBase[NB] = E;
}

// bucket scatter: pos = bucketBase[nb] + blkpre[blk][nb] + LDS-rank. Payload packs
// src(17b)|localdst(9b). Same-bucket edges of one block -> contiguous run -> L2 merges.
__global__ __launch_bounds__(256) void k_binscatter(const int* __restrict__ src,
                                                    const int* __restrict__ dst,
                                                    const float* __restrict__ ea,
                                                    const float* __restrict__ ew,
                                                    const float* __restrict__ eb,
                                                    const int* __restrict__ blkpre,
                                                    const int* __restrict__ bucketBase,
                                                    float4* __restrict__ sorted,
                                                    int E, int CHUNK, int NB) {
    extern __shared__ unsigned brun[];  // NB u32
    for (int i = threadIdx.x; i < NB; i += 256) brun[i] = 0u;
    __syncthreads();
    const int* bp = blkpre + (size_t)blockIdx.x * NB;
    int beg = blockIdx.x * CHUNK, end = min(E, beg + CHUNK);
    for (int base = beg + (int)threadIdx.x * 4; base < end; base += 256 * 4) {
        if (base + 3 < end) {
            i4 s = __builtin_nontemporal_load((const i4*)(src + base));
            i4 d = __builtin_nontemporal_load((const i4*)(dst + base));
            f4 a = __builtin_nontemporal_load((const f4*)(ea + base));
            f4 w = __builtin_nontemporal_load((const f4*)(ew + base));
            f4 b = __builtin_nontemporal_load((const f4*)(eb + base));
            int ds[4] = {d.x, d.y, d.z, d.w};
            int ss[4] = {s.x, s.y, s.z, s.w};
            float as[4] = {a.x, a.y, a.z, a.w};
            float ws[4] = {w.x, w.y, w.z, w.w};
            float bs[4] = {b.x, b.y, b.z, b.w};
#pragma unroll
            for (int k = 0; k < 4; ++k) {
                int nb = (unsigned)ds[k] >> BKT_SHIFT;
                int ld = ds[k] & (BKT - 1);
                unsigned r = atomicAdd(&brun[nb], 1u);
                int pos = bucketBase[nb] + bp[nb] + (int)r;
                sorted[pos] = make_float4(
                    __int_as_float(((unsigned)ss[k] << BKT_SHIFT) | (unsigned)ld),
                    as[k], ws[k], bs[k]);
            }
        } else {
            for (int e = base; e < end; ++e) {
                int dd = dst[e];
                int nb = (unsigned)dd >> BKT_SHIFT;
                int ld = dd & (BKT - 1);
                unsigned r = atomicAdd(&brun[nb], 1u);
                int pos = bucketBase[nb] + bp[nb] + (int)r;
                sorted[pos] = make_float4(
                    __int_as_float(((unsigned)src[e] << BKT_SHIFT) | (unsigned)ld),
                    ea[e], ew[e], eb[e]);
            }
        }
    }
}

// one block per bucket: stream payload, edge blend, accumulate in LDS (float atomics),
// then node blend + contiguous out writes. Replaces rank/offsets/gather entirely.
__global__ __launch_bounds__(512) void k_bucket_acc(const float4* __restrict__ sorted,
                                                    const int* __restrict__ bucketBase,
                                                    const float* __restrict__ xT,
                                                    const float* __restrict__ na,
                                                    const float* __restrict__ nw,
                                                    const float* __restrict__ nbv,
                                                    float* __restrict__ out, int N) {
    __shared__ float acc[BATCH * BKT];  // [b][ld], 32 KB
    for (int i = threadIdx.x; i < BATCH * BKT; i += 512) acc[i] = 0.f;
    __syncthreads();
    int nb = blockIdx.x;
    int n0 = nb << BKT_SHIFT;
    int beg = bucketBase[nb], end = bucketBase[nb + 1];
    const f4* so = (const f4*)sorted;
    for (int r = beg + (int)threadIdx.x; r < end; r += 512) {
        f4 pl = __builtin_nontemporal_load(&so[r]);
        unsigned u = (unsigned)__float_as_int(pl.x);
        int s = (int)(u >> BKT_SHIFT);
        int ld = (int)(u & (BKT - 1u));
        float al = pl.y, w = pl.z, bb = pl.w;
        const float4* xs = (const float4*)(xT + (size_t)s * BATCH);
#pragma unroll
        for (int i = 0; i < 4; ++i) {
            float4 xv = xs[i];
            atomicAdd(&acc[(i * 4 + 0) * BKT + ld], blend(w * xv.x + bb, al));
            atomicAdd(&acc[(i * 4 + 1) * BKT + ld], blend(w * xv.y + bb, al));
            atomicAdd(&acc[(i * 4 + 2) * BKT + ld], blend(w * xv.z + bb, al));
            atomicAdd(&acc[(i * 4 + 3) * BKT + ld], blend(w * xv.w + bb, al));
        }
    }
    __syncthreads();
    for (int i = threadIdx.x; i < BATCH * BKT; i += 512) {
        int ld = i & (BKT - 1);
        int b = i >> BKT_SHIFT;
        int n = n0 + ld;
        if (n < N) {
            float y = acc[b * BKT + ld];
            out[(size_t)b * N + n] = blend(nw[n] * y + nbv[n], na[n]);
        }
    }
}

// ---------------- fallback 1: device-atomic rank path (proven, round 5) ----------------

__global__ __launch_bounds__(256) void k_hist_rank(const int* __restrict__ dst,
                                                   int* __restrict__ counts,
                                                   int* __restrict__ rank, int E) {
    int i = blockIdx.x * blockDim.x + threadIdx.x;
    int base = i * 4;
    if (base + 3 < E) {
        int4 d = *(const int4*)(dst + base);
        int r0 = atomicAdd(&counts[d.x], 1);
        int r1 = atomicAdd(&counts[d.y], 1);
        int r2 = atomicAdd(&counts[d.z], 1);
        int r3 = atomicAdd(&counts[d.w], 1);
        *(int4*)(rank + base) = make_int4(r0, r1, r2, r3);
    } else {
        for (int e = base; e < E; ++e) rank[e] = atomicAdd(&counts[dst[e]], 1);
    }
}

__global__ __launch_bounds__(256) void k_scan_tiles(const int* __restrict__ counts,
                                                    int* __restrict__ offsets,
                                                    int* __restrict__ tileSums, int N) {
    __shared__ int sdata[256];
    int t = threadIdx.x;
    int base = blockIdx.x * TILE + t * 8;
    int v[8];
    int s = 0;
#pragma unroll
    for (int i = 0; i < 8; ++i) {
        v[i] = (base + i < N) ? counts[base + i] : 0;
        s += v[i];
    }
    sdata[t] = s;
    __syncthreads();
    for (int off = 1; off < 256; off <<= 1) {
        int add = 0;
        if (t >= off) add = sdata[t - off];
        __syncthreads();
        sdata[t] += add;
        __syncthreads();
    }
    int run = sdata[t] - s;
#pragma unroll
    for (int i = 0; i < 8; ++i) {
        if (base + i < N) offsets[base + i] = run;
        run += v[i];
    }
    if (t == 255) tileSums[blockIdx.x] = sdata[255];
}

__global__ __launch_bounds__(256) void k_scan_sums(int* __restrict__ tileSums,
                                                   int* __restrict__ offsets,
                                                   int nTiles, int N, int E) {
    __shared__ int sh[256];
    int t = threadIdx.x;
    int v = (t < nTiles) ? tileSums[t] : 0;
    sh[t] = v;
    __syncthreads();
    for (int off = 1; off < 256; off <<= 1) {
        int add = 0;
        if (t >= off) add = sh[t - off];
        __syncthreads();
        sh[t] += add;
        __syncthreads();
    }
    if (t < nTiles) tileSums[t] = sh[t] - v;
    if (t == 0) offsets[N] = E;
}

__global__ __launch_bounds__(256) void k_add(int* __restrict__ offsets,
                                             const int* __restrict__ tileSums, int N) {
    int i = blockIdx.x * blockDim.x + threadIdx.x;
    if (i >= N) return;
    offsets[i] += tileSums[i / TILE];
}

__global__ __launch_bounds__(256) void k_scatter_rank(const int* __restrict__ src,
                                                      const int* __restrict__ dst,
                                                      const float* __restrict__ ea,
                                                      const float* __restrict__ ew,
                                                      const float* __restrict__ eb,
                                                      const int* __restrict__ rank,
                                                      const int* __restrict__ offsets,
                                                      float4* __restrict__ sorted, int E) {
    int i = blockIdx.x * blockDim.x + threadIdx.x;
    int base = i * 4;
    if (base + 3 < E) {
        int4 s = *(const int4*)(src + base);
        int4 d = *(const int4*)(dst + base);
        int4 r = *(const int4*)(rank + base);
        float4 a = *(const float4*)(ea + base);
        float4 w = *(const float4*)(ew + base);
        float4 b = *(const float4*)(eb + base);
        sorted[offsets[d.x] + r.x] = make_float4(__int_as_float(s.x), a.x, w.x, b.x);
        sorted[offsets[d.y] + r.y] = make_float4(__int_as_float(s.y), a.y, w.y, b.y);
        sorted[offsets[d.z] + r.z] = make_float4(__int_as_float(s.z), a.z, w.z, b.z);
        sorted[offsets[d.w] + r.w] = make_float4(__int_as_float(s.w), a.w, w.w, b.w);
    } else {
        for (int e = base; e < E; ++e)
            sorted[offsets[dst[e]] + rank[e]] =
                make_float4(__int_as_float(src[e]), ea[e], ew[e], eb[e]);
    }
}

__global__ __launch_bounds__(256) void k_gather(const float4* __restrict__ sorted,
                                                const int* __restrict__ offsets,
                                                const float* __restrict__ xT,
                                                const float* __restrict__ na,
                                                const float* __restrict__ nw,
                                                const float* __restrict__ nbv,
                                                float* __restrict__ out, int N) {
    int t = blockIdx.x * blockDim.x + threadIdx.x;
    int n = t >> 2;
    int j = t & 3;
    if (n >= N) return;
    int beg = offsets[n], end = offsets[n + 1];
    float4 acc = make_float4(0.f, 0.f, 0.f, 0.f);
    for (int r = beg; r < end; ++r) {
        float4 pl = sorted[r];
        int s = __float_as_int(pl.x);
        float4 xv = *(const float4*)(xT + (size_t)s * BATCH + j * 4);
        acc.x += blend(pl.z * xv.x + pl.w, pl.y);
        acc.y += blend(pl.z * xv.y + pl.w, pl.y);
        acc.z += blend(pl.z * xv.z + pl.w, pl.y);
        acc.w += blend(pl.z * xv.w + pl.w, pl.y);
    }
    float a = na[n], w = nw[n], bb = nbv[n];
    out[(size_t)(4 * j + 0) * N + n] = blend(w * acc.x + bb, a);
    out[(size_t)(4 * j + 1) * N + n] = blend(w * acc.y + bb, a);
    out[(size_t)(4 * j + 2) * N + n] = blend(w * acc.z + bb, a);
    out[(size_t)(4 * j + 3) * N + n] = blend(w * acc.w + bb, a);
}

// ---------------- fallback 2: direct atomic path ----------------

__global__ __launch_bounds__(256) void k_edge_direct(const int* __restrict__ src,
                                                     const int* __restrict__ dst,
                                                     const float* __restrict__ ea,
                                                     const float* __restrict__ ew,
                                                     const float* __restrict__ eb,
                                                     const float* __restrict__ x,
                                                     float* __restrict__ out, int N, int E) {
    int e = blockIdx.x * blockDim.x + threadIdx.x;
    if (e >= E) return;
    int s = src[e], d = dst[e];
    float a = ea[e], w = ew[e], bb = eb[e];
#pragma unroll
    for (int b = 0; b < BATCH; ++b) {
        float xv = x[(size_t)b * N + s];
        unsafeAtomicAdd(out + (size_t)b * N + d, blend(w * xv + bb, a));
    }
}

__global__ __launch_bounds__(256) void k_node_inplace(const float* __restrict__ na,
                                                      const float* __restrict__ nw,
                                                      const float* __restrict__ nbv,
                                                      float* __restrict__ out, int N) {
    int n = blockIdx.x * blockDim.x + threadIdx.x;
    if (n >= N) return;
    float a = na[n], w = nw[n], bb = nbv[n];
#pragma unroll
    for (int b = 0; b < BATCH; ++b) {
        size_t idx = (size_t)b * N + n;
        out[idx] = blend(w * out[idx] + bb, a);
    }
}

extern "C" void kernel_launch(void* const* d_in, const int* in_sizes, int n_in,
                              void* d_out, int out_size, void* d_ws, size_t ws_size,
                              hipStream_t stream) {
    const float* x   = (const float*)d_in[0];
    const int*   src = (const int*)  d_in[1];
    const int*   dst = (const int*)  d_in[2];
    const float* ea  = (const float*)d_in[3];
    const float* ew  = (const float*)d_in[4];
    const float* eb  = (const float*)d_in[5];
    const float* na  = (const float*)d_in[6];
    const float* nw  = (const float*)d_in[7];
    const float* nb  = (const float*)d_in[8];
    float* out = (float*)d_out;

    const int E = in_sizes[1];
    const int N = in_sizes[6];
    const int bt = 256;
    const int NB = (N + BKT - 1) >> BKT_SHIFT;
    const int nTiles = (N + TILE - 1) / TILE;
    const int gE4 = ((E + 3) / 4 + bt - 1) / bt;

    // workspace layout
    float*  xT       = (float*)d_ws;                       // N*16 floats
    float4* sorted   = (float4*)(xT + (size_t)N * BATCH);  // E float4
    int*    blkcnt   = (int*)(sorted + (size_t)E);         // NCHUNK*NB (bucket path)
    int*    bucketBase = blkcnt + (size_t)NCHUNK * NB;     // NB+1

    size_t need_bkt = (size_t)N * BATCH * sizeof(float) + (size_t)E * sizeof(float4) +
                      ((size_t)NCHUNK * NB + NB + 1) * sizeof(int);
    // rank-path layout: rank(E), counts(N), offsets(N+1), tileSums(256) after sorted
    size_t need_rank = (size_t)N * BATCH * sizeof(float) + (size_t)E * sizeof(float4) +
                       ((size_t)E + 2 * N + 1 + 256) * sizeof(int);

    if (NB <= 256 && ws_size >= need_bkt) {
        int CHUNK = ((E + NCHUNK - 1) / NCHUNK + 3) & ~3;
        k_transpose<<<(N + bt - 1) / bt, bt, 0, stream>>>(x, xT, N);
        k_bhist<<<NCHUNK, bt, (size_t)NB * 4, stream>>>(dst, blkcnt, E, CHUNK, NB);
        k_bscan<<<1, 256, 0, stream>>>(blkcnt, bucketBase, NB, NCHUNK, E);
        k_binscatter<<<NCHUNK, bt, (size_t)NB * 4, stream>>>(src, dst, ea, ew, eb, blkcnt,
                                                             bucketBase, sorted, E, CHUNK, NB);
        k_bucket_acc<<<NB, 512, 0, stream>>>(sorted, bucketBase, xT, na, nw, nb, out, N);
    } else if (ws_size >= need_rank && nTiles <= 256) {
        int* rank     = (int*)(sorted + (size_t)E);
        int* counts   = rank + E;
        int* offsets  = counts + N;
        int* tileSums = offsets + (N + 1);
        (void)hipMemsetAsync(counts, 0, (size_t)N * sizeof(int), stream);
        k_transpose<<<(N + bt - 1) / bt, bt, 0, stream>>>(x, xT, N);
        k_hist_rank<<<gE4, bt, 0, stream>>>(dst, counts, rank, E);
        k_scan_tiles<<<nTiles, 256, 0, stream>>>(counts, offsets, tileSums, N);
        k_scan_sums<<<1, 256, 0, stream>>>(tileSums, offsets, nTiles, N, E);
        k_add<<<(N + bt - 1) / bt, bt, 0, stream>>>(offsets, tileSums, N);
        k_scatter_rank<<<gE4, bt, 0, stream>>>(src, dst, ea, ew, eb, rank, offsets, sorted, E);
        k_gather<<<((size_t)N * 4 + bt - 1) / bt, bt, 0, stream>>>(sorted, offsets, xT,
                                                                   na, nw, nb, out, N);
    } else {
        (void)hipMemsetAsync(d_out, 0, (size_t)out_size * sizeof(float), stream);
        k_edge_direct<<<(E + bt - 1) / bt, bt, 0, stream>>>(src, dst, ea, ew, eb, x, out, N, E);
        k_node_inplace<<<(N + bt - 1) / bt, bt, 0, stream>>>(na, nw, nb, out, N);
    }
}

// Round 17
// 272.014 us; speedup vs baseline: 2.0175x; 2.0175x over previous
//
#include <hip/hip_runtime.h>

#define BATCH 16
#define TILE 2048
#define BKT 256          // nodes per bucket (power of two)
#define BKT_SHIFT 8
#define NCHUNK 256       // blocks for bhist/binscatter
#define FXS 65536.0f     // fixed-point scale for LDS integer accumulation
#define FXI (1.0f / 65536.0f)

// native clang ext-vectors for __builtin_nontemporal_* (HIP_vector_type is rejected)
typedef int   i4 __attribute__((ext_vector_type(4)));
typedef float f4 __attribute__((ext_vector_type(4)));

__device__ __forceinline__ float fast_tanh(float v) {
    float a = fabsf(v);
    float e = __expf(2.0f * a);
    float t = 1.0f - 2.0f / (e + 1.0f);
    return copysignf(t, v);
}

__device__ __forceinline__ float blend(float lin, float alpha) {
    return lin + alpha * (fast_tanh(lin) - lin);
}

// xT[n*B+b] = x[b*N+n]
__global__ __launch_bounds__(256) void k_transpose(const float* __restrict__ x,
                                                   float* __restrict__ xT, int N) {
    int n = blockIdx.x * blockDim.x + threadIdx.x;
    if (n >= N) return;
    float v[BATCH];
#pragma unroll
    for (int b = 0; b < BATCH; ++b) v[b] = x[(size_t)b * N + n];
    float4* dst = (float4*)(xT + (size_t)n * BATCH);
#pragma unroll
    for (int i = 0; i < BATCH / 4; ++i)
        dst[i] = make_float4(v[4 * i], v[4 * i + 1], v[4 * i + 2], v[4 * i + 3]);
}

// per-block bucket histogram (integer LDS counters), written to blkcnt[block][NB]
__global__ __launch_bounds__(256) void k_bhist(const int* __restrict__ dst,
                                               int* __restrict__ blkcnt,
                                               int E, int CHUNK, int NB) {
    extern __shared__ unsigned bc[];  // NB u32
    for (int i = threadIdx.x; i < NB; i += 256) bc[i] = 0u;
    __syncthreads();
    int beg = blockIdx.x * CHUNK, end = min(E, beg + CHUNK);
    for (int base = beg + (int)threadIdx.x * 4; base < end; base += 256 * 4) {
        if (base + 3 < end) {
            i4 d = __builtin_nontemporal_load((const i4*)(dst + base));
            atomicAdd(&bc[(unsigned)d.x >> BKT_SHIFT], 1u);
            atomicAdd(&bc[(unsigned)d.y >> BKT_SHIFT], 1u);
            atomicAdd(&bc[(unsigned)d.z >> BKT_SHIFT], 1u);
            atomicAdd(&bc[(unsigned)d.w >> BKT_SHIFT], 1u);
        } else {
            for (int e = base; e < end; ++e) atomicAdd(&bc[(unsigned)dst[e] >> BKT_SHIFT], 1u);
        }
    }
    __syncthreads();
    int* bo = blkcnt + (size_t)blockIdx.x * NB;
    for (int i = threadIdx.x; i < NB; i += 256) bo[i] = (int)bc[i];
}

// single block, 512 threads: column-scan blkcnt (exclusive, in place) + bucket bases.
// Supports NB <= 512.
__global__ __launch_bounds__(512) void k_bscan(int* __restrict__ blkcnt,
                                               int* __restrict__ bucketBase,
                                               int NB, int nchunk, int E) {
    int t = threadIdx.x;
    int run = 0;
    if (t < NB) {
        for (int blk = 0; blk < nchunk; ++blk) {
            size_t i = (size_t)blk * NB + t;
            int c = blkcnt[i];
            blkcnt[i] = run;
            run += c;
        }
    }
    __shared__ int sh[512];
    int tot = run;
    sh[t] = tot;
    __syncthreads();
    for (int off = 1; off < 512; off <<= 1) {
        int add = (t >= off) ? sh[t - off] : 0;
        __syncthreads();
        sh[t] += add;
        __syncthreads();
    }
    if (t < NB) bucketBase[t] = sh[t] - tot;  // exclusive
    if (t == 0) bucketBase[NB] = E;
}

// bucket scatter: LDS cursor pre-offset with bucketBase+blkpre -> slot = one LDS atomic.
// Payload packs src(17b)<<8 | localdst(8b). Same-bucket edges of one block form a
// contiguous ~512B run (write-clustering for L2 line assembly).
__global__ __launch_bounds__(256) void k_binscatter(const int* __restrict__ src,
                                                    const int* __restrict__ dst,
                                                    const float* __restrict__ ea,
                                                    const float* __restrict__ ew,
                                                    const float* __restrict__ eb,
                                                    const int* __restrict__ blkpre,
                                                    const int* __restrict__ bucketBase,
                                                    float4* __restrict__ sorted,
                                                    int E, int CHUNK, int NB) {
    extern __shared__ unsigned brun[];  // NB u32, init = bucketBase[nb] + blkpre[blk][nb]
    const int* bp = blkpre + (size_t)blockIdx.x * NB;
    for (int i = threadIdx.x; i < NB; i += 256)
        brun[i] = (unsigned)(bucketBase[i] + bp[i]);
    __syncthreads();
    int beg = blockIdx.x * CHUNK, end = min(E, beg + CHUNK);
    for (int base = beg + (int)threadIdx.x * 4; base < end; base += 256 * 4) {
        if (base + 3 < end) {
            i4 s = __builtin_nontemporal_load((const i4*)(src + base));
            i4 d = __builtin_nontemporal_load((const i4*)(dst + base));
            f4 a = __builtin_nontemporal_load((const f4*)(ea + base));
            f4 w = __builtin_nontemporal_load((const f4*)(ew + base));
            f4 b = __builtin_nontemporal_load((const f4*)(eb + base));
            int ds[4] = {d.x, d.y, d.z, d.w};
            int ss[4] = {s.x, s.y, s.z, s.w};
            float as[4] = {a.x, a.y, a.z, a.w};
            float ws[4] = {w.x, w.y, w.z, w.w};
            float bs[4] = {b.x, b.y, b.z, b.w};
#pragma unroll
            for (int k = 0; k < 4; ++k) {
                int nb = (unsigned)ds[k] >> BKT_SHIFT;
                int ld = ds[k] & (BKT - 1);
                int pos = (int)atomicAdd(&brun[nb], 1u);
                sorted[pos] = make_float4(
                    __int_as_float(((unsigned)ss[k] << BKT_SHIFT) | (unsigned)ld),
                    as[k], ws[k], bs[k]);
            }
        } else {
            for (int e = base; e < end; ++e) {
                int dd = dst[e];
                int nb = (unsigned)dd >> BKT_SHIFT;
                int ld = dd & (BKT - 1);
                int pos = (int)atomicAdd(&brun[nb], 1u);
                sorted[pos] = make_float4(
                    __int_as_float(((unsigned)src[e] << BKT_SHIFT) | (unsigned)ld),
                    ea[e], ew[e], eb[e]);
            }
        }
    }
}

// one block per bucket: stream payload, edge blend, accumulate FIXED-POINT in LDS via
// NATIVE integer atomics (fp32 LDS atomicAdd CAS-loops without -munsafe-fp-atomics —
// round-16 lesson: 351us). Then node blend + contiguous out writes.
__global__ __launch_bounds__(512) void k_bucket_acc(const float4* __restrict__ sorted,
                                                    const int* __restrict__ bucketBase,
                                                    const float* __restrict__ xT,
                                                    const float* __restrict__ na,
                                                    const float* __restrict__ nw,
                                                    const float* __restrict__ nbv,
                                                    float* __restrict__ out, int N) {
    __shared__ int acc[BATCH * BKT];  // [b][ld], 16 KB, fixed-point 2^16
    for (int i = threadIdx.x; i < BATCH * BKT; i += 512) acc[i] = 0;
    __syncthreads();
    int nb = blockIdx.x;
    int n0 = nb << BKT_SHIFT;
    int beg = bucketBase[nb], end = bucketBase[nb + 1];
    const f4* so = (const f4*)sorted;
    for (int r = beg + (int)threadIdx.x; r < end; r += 512) {
        f4 pl = __builtin_nontemporal_load(&so[r]);
        unsigned u = (unsigned)__float_as_int(pl.x);
        int s = (int)(u >> BKT_SHIFT);
        int ld = (int)(u & (BKT - 1u));
        float al = pl.y, w = pl.z, bb = pl.w;
        const float4* xs = (const float4*)(xT + (size_t)s * BATCH);
#pragma unroll
        for (int i = 0; i < 4; ++i) {
            float4 xv = xs[i];
            atomicAdd(&acc[(i * 4 + 0) * BKT + ld], __float2int_rn(blend(w * xv.x + bb, al) * FXS));
            atomicAdd(&acc[(i * 4 + 1) * BKT + ld], __float2int_rn(blend(w * xv.y + bb, al) * FXS));
            atomicAdd(&acc[(i * 4 + 2) * BKT + ld], __float2int_rn(blend(w * xv.z + bb, al) * FXS));
            atomicAdd(&acc[(i * 4 + 3) * BKT + ld], __float2int_rn(blend(w * xv.w + bb, al) * FXS));
        }
    }
    __syncthreads();
    for (int i = threadIdx.x; i < BATCH * BKT; i += 512) {
        int ld = i & (BKT - 1);
        int b = i >> BKT_SHIFT;
        int n = n0 + ld;
        if (n < N) {
            float y = (float)acc[b * BKT + ld] * FXI;
            out[(size_t)b * N + n] = blend(nw[n] * y + nbv[n], na[n]);
        }
    }
}

// ---------------- fallback 1: device-atomic rank path (proven, round 5) ----------------

__global__ __launch_bounds__(256) void k_hist_rank(const int* __restrict__ dst,
                                                   int* __restrict__ counts,
                                                   int* __restrict__ rank, int E) {
    int i = blockIdx.x * blockDim.x + threadIdx.x;
    int base = i * 4;
    if (base + 3 < E) {
        int4 d = *(const int4*)(dst + base);
        int r0 = atomicAdd(&counts[d.x], 1);
        int r1 = atomicAdd(&counts[d.y], 1);
        int r2 = atomicAdd(&counts[d.z], 1);
        int r3 = atomicAdd(&counts[d.w], 1);
        *(int4*)(rank + base) = make_int4(r0, r1, r2, r3);
    } else {
        for (int e = base; e < E; ++e) rank[e] = atomicAdd(&counts[dst[e]], 1);
    }
}

__global__ __launch_bounds__(256) void k_scan_tiles(const int* __restrict__ counts,
                                                    int* __restrict__ offsets,
                                                    int* __restrict__ tileSums, int N) {
    __shared__ int sdata[256];
    int t = threadIdx.x;
    int base = blockIdx.x * TILE + t * 8;
    int v[8];
    int s = 0;
#pragma unroll
    for (int i = 0; i < 8; ++i) {
        v[i] = (base + i < N) ? counts[base + i] : 0;
        s += v[i];
    }
    sdata[t] = s;
    __syncthreads();
    for (int off = 1; off < 256; off <<= 1) {
        int add = 0;
        if (t >= off) add = sdata[t - off];
        __syncthreads();
        sdata[t] += add;
        __syncthreads();
    }
    int run = sdata[t] - s;
#pragma unroll
    for (int i = 0; i < 8; ++i) {
        if (base + i < N) offsets[base + i] = run;
        run += v[i];
    }
    if (t == 255) tileSums[blockIdx.x] = sdata[255];
}

__global__ __launch_bounds__(256) void k_scan_sums(int* __restrict__ tileSums,
                                                   int* __restrict__ offsets,
                                                   int nTiles, int N, int E) {
    __shared__ int sh[256];
    int t = threadIdx.x;
    int v = (t < nTiles) ? tileSums[t] : 0;
    sh[t] = v;
    __syncthreads();
    for (int off = 1; off < 256; off <<= 1) {
        int add = 0;
        if (t >= off) add = sh[t - off];
        __syncthreads();
        sh[t] += add;
        __syncthreads();
    }
    if (t < nTiles) tileSums[t] = sh[t] - v;
    if (t == 0) offsets[N] = E;
}

__global__ __launch_bounds__(256) void k_add(int* __restrict__ offsets,
                                             const int* __restrict__ tileSums, int N) {
    int i = blockIdx.x * blockDim.x + threadIdx.x;
    if (i >= N) return;
    offsets[i] += tileSums[i / TILE];
}

__global__ __launch_bounds__(256) void k_scatter_rank(const int* __restrict__ src,
                                                      const int* __restrict__ dst,
                                                      const float* __restrict__ ea,
                                                      const float* __restrict__ ew,
                                                      const float* __restrict__ eb,
                                                      const int* __restrict__ rank,
                                                      const int* __restrict__ offsets,
                                                      float4* __restrict__ sorted, int E) {
    int i = blockIdx.x * blockDim.x + threadIdx.x;
    int base = i * 4;
    if (base + 3 < E) {
        int4 s = *(const int4*)(src + base);
        int4 d = *(const int4*)(dst + base);
        int4 r = *(const int4*)(rank + base);
        float4 a = *(const float4*)(ea + base);
        float4 w = *(const float4*)(ew + base);
        float4 b = *(const float4*)(eb + base);
        sorted[offsets[d.x] + r.x] = make_float4(__int_as_float(s.x), a.x, w.x, b.x);
        sorted[offsets[d.y] + r.y] = make_float4(__int_as_float(s.y), a.y, w.y, b.y);
        sorted[offsets[d.z] + r.z] = make_float4(__int_as_float(s.z), a.z, w.z, b.z);
        sorted[offsets[d.w] + r.w] = make_float4(__int_as_float(s.w), a.w, w.w, b.w);
    } else {
        for (int e = base; e < E; ++e)
            sorted[offsets[dst[e]] + rank[e]] =
                make_float4(__int_as_float(src[e]), ea[e], ew[e], eb[e]);
    }
}

__global__ __launch_bounds__(256) void k_gather(const float4* __restrict__ sorted,
                                                const int* __restrict__ offsets,
                                                const float* __restrict__ xT,
                                                const float* __restrict__ na,
                                                const float* __restrict__ nw,
                                                const float* __restrict__ nbv,
                                                float* __restrict__ out, int N) {
    int t = blockIdx.x * blockDim.x + threadIdx.x;
    int n = t >> 2;
    int j = t & 3;
    if (n >= N) return;
    int beg = offsets[n], end = offsets[n + 1];
    float4 acc = make_float4(0.f, 0.f, 0.f, 0.f);
    for (int r = beg; r < end; ++r) {
        float4 pl = sorted[r];
        int s = __float_as_int(pl.x);
        float4 xv = *(const float4*)(xT + (size_t)s * BATCH + j * 4);
        acc.x += blend(pl.z * xv.x + pl.w, pl.y);
        acc.y += blend(pl.z * xv.y + pl.w, pl.y);
        acc.z += blend(pl.z * xv.z + pl.w, pl.y);
        acc.w += blend(pl.z * xv.w + pl.w, pl.y);
    }
    float a = na[n], w = nw[n], bb = nbv[n];
    out[(size_t)(4 * j + 0) * N + n] = blend(w * acc.x + bb, a);
    out[(size_t)(4 * j + 1) * N + n] = blend(w * acc.y + bb, a);
    out[(size_t)(4 * j + 2) * N + n] = blend(w * acc.z + bb, a);
    out[(size_t)(4 * j + 3) * N + n] = blend(w * acc.w + bb, a);
}

// ---------------- fallback 2: direct atomic path ----------------

__global__ __launch_bounds__(256) void k_edge_direct(const int* __restrict__ src,
                                                     const int* __restrict__ dst,
                                                     const float* __restrict__ ea,
                                                     const float* __restrict__ ew,
                                                     const float* __restrict__ eb,
                                                     const float* __restrict__ x,
                                                     float* __restrict__ out, int N, int E) {
    int e = blockIdx.x * blockDim.x + threadIdx.x;
    if (e >= E) return;
    int s = src[e], d = dst[e];
    float a = ea[e], w = ew[e], bb = eb[e];
#pragma unroll
    for (int b = 0; b < BATCH; ++b) {
        float xv = x[(size_t)b * N + s];
        unsafeAtomicAdd(out + (size_t)b * N + d, blend(w * xv + bb, a));
    }
}

__global__ __launch_bounds__(256) void k_node_inplace(const float* __restrict__ na,
                                                      const float* __restrict__ nw,
                                                      const float* __restrict__ nbv,
                                                      float* __restrict__ out, int N) {
    int n = blockIdx.x * blockDim.x + threadIdx.x;
    if (n >= N) return;
    float a = na[n], w = nw[n], bb = nbv[n];
#pragma unroll
    for (int b = 0; b < BATCH; ++b) {
        size_t idx = (size_t)b * N + n;
        out[idx] = blend(w * out[idx] + bb, a);
    }
}

extern "C" void kernel_launch(void* const* d_in, const int* in_sizes, int n_in,
                              void* d_out, int out_size, void* d_ws, size_t ws_size,
                              hipStream_t stream) {
    const float* x   = (const float*)d_in[0];
    const int*   src = (const int*)  d_in[1];
    const int*   dst = (const int*)  d_in[2];
    const float* ea  = (const float*)d_in[3];
    const float* ew  = (const float*)d_in[4];
    const float* eb  = (const float*)d_in[5];
    const float* na  = (const float*)d_in[6];
    const float* nw  = (const float*)d_in[7];
    const float* nb  = (const float*)d_in[8];
    float* out = (float*)d_out;

    const int E = in_sizes[1];
    const int N = in_sizes[6];
    const int bt = 256;
    const int NB = (N + BKT - 1) >> BKT_SHIFT;
    const int nTiles = (N + TILE - 1) / TILE;
    const int gE4 = ((E + 3) / 4 + bt - 1) / bt;

    // workspace layout
    float*  xT       = (float*)d_ws;                       // N*16 floats
    float4* sorted   = (float4*)(xT + (size_t)N * BATCH);  // E float4
    int*    blkcnt   = (int*)(sorted + (size_t)E);         // NCHUNK*NB (bucket path)
    int*    bucketBase = blkcnt + (size_t)NCHUNK * NB;     // NB+1

    size_t need_bkt = (size_t)N * BATCH * sizeof(float) + (size_t)E * sizeof(float4) +
                      ((size_t)NCHUNK * NB + NB + 1) * sizeof(int);
    size_t need_rank = (size_t)N * BATCH * sizeof(float) + (size_t)E * sizeof(float4) +
                       ((size_t)E + 2 * N + 1 + 256) * sizeof(int);

    if (NB <= 512 && ws_size >= need_bkt) {
        int CHUNK = ((E + NCHUNK - 1) / NCHUNK + 3) & ~3;
        k_transpose<<<(N + bt - 1) / bt, bt, 0, stream>>>(x, xT, N);
        k_bhist<<<NCHUNK, bt, (size_t)NB * 4, stream>>>(dst, blkcnt, E, CHUNK, NB);
        k_bscan<<<1, 512, 0, stream>>>(blkcnt, bucketBase, NB, NCHUNK, E);
        k_binscatter<<<NCHUNK, bt, (size_t)NB * 4, stream>>>(src, dst, ea, ew, eb, blkcnt,
                                                             bucketBase, sorted, E, CHUNK, NB);
        k_bucket_acc<<<NB, 512, 0, stream>>>(sorted, bucketBase, xT, na, nw, nb, out, N);
    } else if (ws_size >= need_rank && nTiles <= 256) {
        int* rank     = (int*)(sorted + (size_t)E);
        int* counts   = rank + E;
        int* offsets  = counts + N;
        int* tileSums = offsets + (N + 1);
        (void)hipMemsetAsync(counts, 0, (size_t)N * sizeof(int), stream);
        k_transpose<<<(N + bt - 1) / bt, bt, 0, stream>>>(x, xT, N);
        k_hist_rank<<<gE4, bt, 0, stream>>>(dst, counts, rank, E);
        k_scan_tiles<<<nTiles, 256, 0, stream>>>(counts, offsets, tileSums, N);
        k_scan_sums<<<1, 256, 0, stream>>>(tileSums, offsets, nTiles, N, E);
        k_add<<<(N + bt - 1) / bt, bt, 0, stream>>>(offsets, tileSums, N);
        k_scatter_rank<<<gE4, bt, 0, stream>>>(src, dst, ea, ew, eb, rank, offsets, sorted, E);
        k_gather<<<((size_t)N * 4 + bt - 1) / bt, bt, 0, stream>>>(sorted, offsets, xT,
                                                                   na, nw, nb, out, N);
    } else {
        (void)hipMemsetAsync(d_out, 0, (size_t)out_size * sizeof(float), stream);
        k_edge_direct<<<(E + bt - 1) / bt, bt, 0, stream>>>(src, dst, ea, ew, eb, x, out, N, E);
        k_node_inplace<<<(N + bt - 1) / bt, bt, 0, stream>>>(na, nw, nb, out, N);
    }
}